// Round 18
// baseline (1014.440 us; speedup 1.0000x reference)
//
#include <hip/hip_runtime.h>
#include <math.h>

#define PI 3.14159265358979323846

// ---------------- helpers ----------------
__device__ inline int iabs(int x){ return x < 0 ? -x : x; }

__device__ __host__ constexpr int packed_off(int l){
    // sum_{m<l} (m+1)(2m+1)
    return ((l-1)*l*(2*l-1))/3 + (3*l*(l-1))/2 + l;
}

__device__ inline void cadd_mul(float2& acc, float2 a, float2 b){ // acc += a*b
    acc.x += a.x*b.x - a.y*b.y;
    acc.y += a.x*b.y + a.y*b.x;
}
__device__ inline void cadd_mulc(float2& acc, float2 a, float2 b){ // acc += a*conj(b)
    acc.x += a.x*b.x + a.y*b.y;
    acc.y += a.y*b.x - a.x*b.y;
}

__device__ inline double dpowi(double x, int n){
    double r = 1.0;
    for (int i = 0; i < n; ++i) r *= x;
    return r;
}

// d^l_{a,b}(beta) = <l a| exp(-i beta Jy) |l b>
__device__ double wigner_d(int l, int a, int b, double beta, const double* sf)
{
    double cb = cos(0.5*beta), sb = sin(0.5*beta);
    int smin = max(0, b - a);
    int smax = min(l + b, l - a);
    if (smin > smax) return 0.0;
    double pref = sqrt(sf[l+a]*sf[l-a]*sf[l+b]*sf[l-b]);
    double t = dpowi(cb, 2*l + b - a - 2*smin) * dpowi(sb, a - b + 2*smin);
    if ((a - b + smin) & 1) t = -t;
    double r = -(sb*sb)/(cb*cb);
    double sum = 0.0;
    for (int s = smin; s <= smax; ++s){
        sum += t / (sf[l+b-s]*sf[s]*sf[a-b+s]*sf[l-a-s]);
        t *= r;
    }
    return pref * sum;
}

// ---------------- constants kernels ----------------
__global__ void k_wq(double* wq)
{
    int i = blockIdx.x*blockDim.x + threadIdx.x;
    int b, k, off;
    if (i < 128){ b = 64; k = i;      off = 0;   }
    else if (i < 168){ b = 20; k = i-128; off = 128; }
    else if (i < 188){ b = 10; k = i-168; off = 168; }
    else return;
    double beta = PI*(2*k+1)/(4.0*b);
    double s = 0.0;
    for (int j = 0; j < b; ++j) s += sin((2*j+1)*beta)/(2*j+1);
    wq[off+k] = (2.0/b)*sin(beta)*s;
}

// jhalf=1: generate only rows j >= c0.
// klayout=0: out[((l*NB+k)*J+j)*J+n];  klayout=1: out[((k*L+l)*J+j)*J+n]
__global__ void k_wig_full(float* __restrict__ out, const double* __restrict__ wq,
                           int L, int J, int NB, double denom, double beta_fix,
                           double factor, int mul2l1, int klayout, int jhalf)
{
    __shared__ double sf[40];
    if (threadIdx.x == 0){ sf[0]=1.0; for (int i=1;i<40;i++) sf[i]=sf[i-1]*i; }
    __syncthreads();
    int c0 = (J-1)/2;
    int JROWS = jhalf ? (J+1)/2 : J;
    int idx = blockIdx.x*blockDim.x + threadIdx.x;
    int total = L*NB*JROWS*J;
    if (idx >= total) return;
    int n = idx % J;
    int jj = (idx/J) % JROWS;
    int j = jhalf ? (c0 + jj) : jj;
    int k = (idx/(J*JROWS)) % NB;
    int l = idx/(J*JROWS*NB);
    int mj = j - c0, mn = n - c0;
    float v = 0.f;
    if (iabs(mj) <= l && iabs(mn) <= l){
        double beta = (denom > 0.0) ? PI*(2*k+1)/denom : beta_fix;
        double d = wigner_d(l, mj, mn, beta, sf);
        double mlt = factor * (mul2l1 ? (2.0*l + 1.0) : 1.0);
        if (wq) mlt *= wq[k];
        v = (float)(d*mlt);
    }
    size_t oidx = klayout ? ((size_t)(k*L + l)*J + j)*J + n
                          : ((size_t)(l*NB + k)*J + j)*J + n;
    out[oidx] = v;
}

// column table [l][k][j]; jhalf=1: only j >= c0
__global__ void k_wig_col(float* __restrict__ out, const double* __restrict__ wq,
                          int L, int J, int NB, double denom, double beta_fix, double factor,
                          int jhalf)
{
    __shared__ double sf[40];
    if (threadIdx.x == 0){ sf[0]=1.0; for (int i=1;i<40;i++) sf[i]=sf[i-1]*i; }
    __syncthreads();
    int c0 = (J-1)/2;
    int JROWS = jhalf ? (J+1)/2 : J;
    int idx = blockIdx.x*blockDim.x + threadIdx.x;
    int total = L*NB*JROWS;
    if (idx >= total) return;
    int jj = idx % JROWS;
    int j = jhalf ? (c0 + jj) : jj;
    int k = (idx/JROWS) % NB;
    int l = idx/(JROWS*NB);
    int mj = j - c0;
    float v = 0.f;
    if (iabs(mj) <= l){
        double beta = (denom > 0.0) ? PI*(2*k+1)/denom : beta_fix;
        double d = wigner_d(l, mj, 0, beta, sf);
        double mlt = factor;
        if (wq) mlt *= wq[k];
        v = (float)(d*mlt);
    }
    out[(size_t)(l*NB + k)*J + j] = v;
}

// out[r*C+c] = exp(sgn*2*pi*i*(r-r0)*(c-c0)/N)
__global__ void k_expmat(float2* __restrict__ out, int R, int C, int r0, int c0, int N, double sgn)
{
    int i = blockIdx.x*blockDim.x + threadIdx.x;
    if (i >= R*C) return;
    int c = i % C, r = i / C;
    double ang = sgn*2.0*PI * (double)((r - r0)*(c - c0)) / (double)N;
    out[i] = make_float2((float)cos(ang), (float)sin(ang));
}

// ---------------- layer 1 ----------------
// only j >= 19 (k_fx1 reads only upper rows)
__global__ __launch_bounds__(256) void k_dft1(const float* __restrict__ x,
    const float2* __restrict__ E1, float2* __restrict__ xh)
{
    __shared__ float2 sE[4992];     // [a:128][j:39]
    __shared__ float rows[2048];    // 16 rows x 128
    int r0 = blockIdx.x * 16;       // row = bf*128+k, 12288 rows, 768 blocks
    int tid = threadIdx.x;
    for (int i = tid; i < 4992; i += 256) sE[i] = E1[i];
    for (int i = tid; i < 2048; i += 256) rows[i] = x[(size_t)r0*128 + i];
    __syncthreads();
    for (int i = tid; i < 320; i += 256){   // i = kl*20 + jj, j = jj+19
        int jj = i % 20, kl = i / 20;
        int j = jj + 19;
        const float* row = &rows[kl*128];
        float2 acc = make_float2(0.f, 0.f);
        for (int a = 0; a < 128; ++a){
            float v = row[a];
            float2 e = sE[a*39 + j];
            acc.x += v*e.x; acc.y += v*e.y;
        }
        xh[(size_t)(r0 + kl)*39 + j] = acc;
    }
}

// Fx1 rows j>=c0 only (full layout, lower rows never read)
__global__ void k_fx1(const float* __restrict__ ana, const float2* __restrict__ xh,
                      float2* __restrict__ Fx)
{
    int i = blockIdx.x*blockDim.x + threadIdx.x;
    if (i >= 400) return;           // l*20+hj, l<20, hj<20
    int hj = i % 20, l = i / 20;
    int j = hj + 19;
    int bf = blockIdx.y;  // 96
    const float*  ar = ana + (size_t)l*4992 + j;
    const float2* xr = xh + (size_t)bf*4992 + j;
    float2 acc = make_float2(0.f, 0.f);
    for (int k = 0; k < 128; ++k){
        float a = ar[k*39];
        float2 v = xr[k*39];
        acc.x += a*v.x; acc.y += a*v.y;
    }
    Fx[(size_t)(l*39 + j)*96 + bf] = acc;
}

// wh[(j*F+f)*O+o]
__global__ void k_wh(float2* __restrict__ wh, const float* __restrict__ w,
                     int J, int P, int F, int O, double sgn)
{
    __shared__ float2 tw[128];
    int tid = threadIdx.x;
    if (tid < P){
        double a = sgn*2.0*PI*tid/P;
        tw[tid] = make_float2((float)cos(a), (float)sin(a));
    }
    __syncthreads();
    int idx = blockIdx.x*blockDim.x + tid;
    if (idx >= J*F*O) return;
    int o = idx % O;
    int f = (idx/O) % F;
    int j = idx/(O*F);
    int mj = j - (J-1)/2;
    int step = ((mj % P) + P) % P;
    const float* wr = w + (f*O+o)*P;
    float2 acc = make_float2(0.f, 0.f);
    int t = 0;
    for (int p = 0; p < P; ++p){
        float v = wr[p];
        acc.x += v*tw[t].x; acc.y += v*tw[t].y;
        t += step; if (t >= P) t -= P;
    }
    wh[idx] = acc;
}

// packed triangular Z1c[bo][ off(l) + hj*(2l+1) + (n-19+l) ] — direct packed-domain map
__global__ void k_z1(const float2* __restrict__ Fx, const float2* __restrict__ wh,
                     const float* __restrict__ half1, float2* __restrict__ Z1c)
{
    int i = blockIdx.x*blockDim.x + threadIdx.x;
    if (i >= 5530) return;
    int bo = blockIdx.y;             // 0..319 (16 b x 20 o)
    // find l: packed_off(l) <= i < packed_off(l+1), incremental
    int l = 0, off = 0;
    #pragma unroll 1
    while (l < 19){
        int next = off + (l+1)*(2*l+1);
        if (i < next) break;
        off = next; ++l;
    }
    int rem = i - off;
    int w = 2*l + 1;
    int hj = rem / w;
    int n = rem % w + 19 - l;
    int j = hj + 19;
    int b = bo/20, o = bo % 20;
    float h = half1[l*39 + n] * (1.f/sqrtf(128.f*6.f));
    const float2* fx = Fx + (size_t)(l*39 + j)*96 + b*6;
    const float2* wv = wh + (size_t)n*120 + o;
    float2 acc = make_float2(0.f, 0.f);
    for (int f = 0; f < 6; ++f) cadd_mulc(acc, fx[f], wv[(size_t)f*20]);
    Z1c[(size_t)bo*5530 + i] = make_float2(acc.x*h, acc.y*h);
}

// ---------------- generic inverse SO3 transform (Hermitian-folded, multi-k) ----------------
// PACKED=1: Z triangular-packed [bo][off(l)+hj*(2l+1)+(n-c0+l)], PTOT=packed_off(L).
// PACKED=0: Z dense [bo][(l*JH+hj)*J+n].
// Phases 2/3: 2x4 register tiles.
template<int L, int J, int K, int KB, int N, int O, int BS, int PACKED>
__global__ __launch_bounds__(BS) void k_idft_t(const float2* __restrict__ Z,
    const float* __restrict__ syn, const float2* __restrict__ W,
    const float* __restrict__ bias, float* __restrict__ out)
{
    constexpr int JJ = J*J, NN = N*N, c0 = (J-1)/2;
    constexpr int JH = (J+1)/2;
    constexpr int JHJ = JH*J;
    constexpr int LHJ = L*JHJ;
    constexpr int PTOT = packed_off(L);
    constexpr int KG = K/KB;
    constexpr int SLOTS = (JHJ + BS - 1)/BS;
    __shared__ float2 sM[KB*JHJ];
    __shared__ float2 sT[JH*N];
    __shared__ float2 sW[J*N];
    int bid = blockIdx.x;
    int kg = bid % KG;
    int bo = bid / KG;
    int k0 = kg*KB;
    int tid = threadIdx.x;

    for (int i = tid; i < J*N; i += BS) sW[i] = W[i];

    float2 acc[SLOTS][KB];
    #pragma unroll
    for (int s = 0; s < SLOTS; ++s)
        #pragma unroll
        for (int kb = 0; kb < KB; ++kb) acc[s][kb] = make_float2(0.f, 0.f);
    #pragma unroll
    for (int s = 0; s < SLOTS; ++s){
        int i = tid + s*BS;
        if (i < JHJ){
            int n = i % J, hj = i / J;
            int lmin = max(hj, iabs(n-c0));
            const float*  sbase = syn + (size_t)c0*J + i;
            if (PACKED){
                const float2* zb = Z + (size_t)bo*PTOT;
                int addr = packed_off(lmin) + hj*(2*lmin+1) + (n - c0 + lmin);
                for (int l = lmin; l < L; ++l){
                    float2 z = zb[addr];
                    addr += (l+1)*(2*l+1) + 2*hj + 1;
                    #pragma unroll
                    for (int kb = 0; kb < KB; ++kb){
                        float s_ = sbase[(size_t)((k0+kb)*L + l)*JJ];
                        acc[s][kb].x += s_*z.x; acc[s][kb].y += s_*z.y;
                    }
                }
            } else {
                const float2* zrow = Z + (size_t)bo*LHJ + i;
                for (int l = lmin; l < L; ++l){
                    float2 z = zrow[(size_t)l*JHJ];
                    #pragma unroll
                    for (int kb = 0; kb < KB; ++kb){
                        float s_ = sbase[(size_t)((k0+kb)*L + l)*JJ];
                        acc[s][kb].x += s_*z.x; acc[s][kb].y += s_*z.y;
                    }
                }
            }
        }
    }
    #pragma unroll
    for (int s = 0; s < SLOTS; ++s){
        int i = tid + s*BS;
        if (i < JHJ){
            #pragma unroll
            for (int kb = 0; kb < KB; ++kb) sM[kb*JHJ + i] = acc[s][kb];
        }
    }
    __syncthreads();

    constexpr int RT = (JH+1)/2, CT4 = (N+3)/4;
    constexpr int AT2 = N/2;
    for (int kb = 0; kb < KB; ++kb){
        const float2* sMk = &sM[kb*JHJ];
        // phase 2: sT[hj*N+g] = sum_n sMk[hj*J+n]*sW[n*N+g]   (2x4 tile)
        for (int t = tid; t < RT*CT4; t += BS){
            int tg = t % CT4, tj = t / CT4;
            int h0 = tj*2, g0 = tg*4;
            int h1 = (h0+1 < JH) ? h0+1 : h0;
            int g1 = (g0+1 < N) ? g0+1 : g0;
            int g2 = (g0+2 < N) ? g0+2 : g0;
            int g3 = (g0+3 < N) ? g0+3 : g0;
            float2 a00 = make_float2(0.f,0.f), a01 = make_float2(0.f,0.f);
            float2 a02 = make_float2(0.f,0.f), a03 = make_float2(0.f,0.f);
            float2 a10 = make_float2(0.f,0.f), a11 = make_float2(0.f,0.f);
            float2 a12 = make_float2(0.f,0.f), a13 = make_float2(0.f,0.f);
            for (int n = 0; n < J; ++n){
                float2 m0 = sMk[h0*J+n], m1 = sMk[h1*J+n];
                float2 w0 = sW[n*N+g0], w1 = sW[n*N+g1];
                float2 w2 = sW[n*N+g2], w3 = sW[n*N+g3];
                cadd_mul(a00, m0, w0); cadd_mul(a01, m0, w1);
                cadd_mul(a02, m0, w2); cadd_mul(a03, m0, w3);
                cadd_mul(a10, m1, w0); cadd_mul(a11, m1, w1);
                cadd_mul(a12, m1, w2); cadd_mul(a13, m1, w3);
            }
            sT[h0*N+g0] = a00;
            if (g0+1 < N) sT[h0*N+g0+1] = a01;
            if (g0+2 < N) sT[h0*N+g0+2] = a02;
            if (g0+3 < N) sT[h0*N+g0+3] = a03;
            if (h0+1 < JH){
                sT[(h0+1)*N+g0] = a10;
                if (g0+1 < N) sT[(h0+1)*N+g0+1] = a11;
                if (g0+2 < N) sT[(h0+1)*N+g0+2] = a12;
                if (g0+3 < N) sT[(h0+1)*N+g0+3] = a13;
            }
        }
        __syncthreads();
        // phase 3 (2x4 tile over (a,g))
        float bb = bias[bo % O];
        float* obase = out + ((size_t)bo*K + k0 + kb)*NN;
        for (int t = tid; t < AT2*CT4; t += BS){
            int tg = t % CT4, ta = t / CT4;
            int a0 = ta*2, g0 = tg*4;
            int g1 = (g0+1 < N) ? g0+1 : g0;
            int g2 = (g0+2 < N) ? g0+2 : g0;
            int g3 = (g0+3 < N) ? g0+3 : g0;
            float2 t00 = sT[g0], t01 = sT[g1], t02 = sT[g2], t03 = sT[g3];
            float r00 = t00.x, r01 = t01.x, r02 = t02.x, r03 = t03.x;
            float r10 = t00.x, r11 = t01.x, r12 = t02.x, r13 = t03.x;
            for (int hj = 1; hj < JH; ++hj){
                float2 wa0 = sW[(c0+hj)*N+a0], wa1 = sW[(c0+hj)*N+a0+1];
                float2 t0 = sT[hj*N+g0], t1 = sT[hj*N+g1];
                float2 t2 = sT[hj*N+g2], t3 = sT[hj*N+g3];
                r00 += 2.f*(t0.x*wa0.x - t0.y*wa0.y);
                r01 += 2.f*(t1.x*wa0.x - t1.y*wa0.y);
                r02 += 2.f*(t2.x*wa0.x - t2.y*wa0.y);
                r03 += 2.f*(t3.x*wa0.x - t3.y*wa0.y);
                r10 += 2.f*(t0.x*wa1.x - t0.y*wa1.y);
                r11 += 2.f*(t1.x*wa1.x - t1.y*wa1.y);
                r12 += 2.f*(t2.x*wa1.x - t2.y*wa1.y);
                r13 += 2.f*(t3.x*wa1.x - t3.y*wa1.y);
            }
            obase[(a0+0)*N+g0] = r00 + bb;
            if (g0+1 < N) obase[(a0+0)*N+g0+1] = r01 + bb;
            if (g0+2 < N) obase[(a0+0)*N+g0+2] = r02 + bb;
            if (g0+3 < N) obase[(a0+0)*N+g0+3] = r03 + bb;
            obase[(a0+1)*N+g0] = r10 + bb;
            if (g0+1 < N) obase[(a0+1)*N+g0+1] = r11 + bb;
            if (g0+2 < N) obase[(a0+1)*N+g0+2] = r12 + bb;
            if (g0+3 < N) obase[(a0+1)*N+g0+3] = r13 + bb;
        }
        __syncthreads();
    }
}

// ---------------- BN stats (float4) ----------------
__global__ __launch_bounds__(256) void k_bn_stats(const float4* __restrict__ x, double* __restrict__ part,
                                                  int B, int C, int S4, int parts)
{
    int c = blockIdx.y, p = blockIdx.x;
    int chunk = (S4 + parts - 1)/parts;
    int s0 = p*chunk, s1e = min(S4, s0 + chunk);
    double a1 = 0.0, a2 = 0.0;
    for (int b = 0; b < B; ++b){
        const float4* base = x + ((size_t)b*C + c)*S4;
        for (int s = s0 + threadIdx.x; s < s1e; s += 256){
            float4 v = base[s];
            a1 += (double)v.x + (double)v.y + (double)v.z + (double)v.w;
            a2 += (double)v.x*v.x + (double)v.y*v.y + (double)v.z*v.z + (double)v.w*v.w;
        }
    }
    __shared__ double r1[256], r2[256];
    r1[threadIdx.x] = a1; r2[threadIdx.x] = a2;
    __syncthreads();
    for (int off = 128; off > 0; off >>= 1){
        if (threadIdx.x < off){ r1[threadIdx.x] += r1[threadIdx.x+off]; r2[threadIdx.x] += r2[threadIdx.x+off]; }
        __syncthreads();
    }
    if (threadIdx.x == 0){ int bid = p*C + c; part[2*bid] = r1[0]; part[2*bid+1] = r2[0]; }
}

__global__ void k_bn_fin(const double* __restrict__ part, const float* __restrict__ g,
                         const float* __restrict__ bt, float2* __restrict__ scsh,
                         int C, int parts, double cnt)
{
    int c = blockIdx.x*blockDim.x + threadIdx.x;
    if (c >= C) return;
    double s1 = 0.0, s2 = 0.0;
    for (int p = 0; p < parts; ++p){ s1 += part[2*(p*C+c)]; s2 += part[2*(p*C+c)+1]; }
    double mu = s1/cnt;
    double var = s2/cnt - mu*mu;
    float sc = (float)(1.0/sqrt(var + 1e-5)) * g[c];
    float sh = bt[c] - (float)mu*sc;
    scsh[c] = make_float2(sc, sh);
}

// ---------------- SO3 layers (2,3) ----------------
// forward 2D DFT with fused BN+ReLU at tile load; j-first ordering.
template<int N, int J>
__global__ __launch_bounds__(256) void k_dft2_t(const float* __restrict__ x, float2* __restrict__ xh,
                                                const float2* __restrict__ EF,
                                                const float2* __restrict__ scsh, int KBETA, int C)
{
    constexpr int JH = (J+1)/2, c0 = (J-1)/2;
    constexpr int NP = N+1;
    __shared__ float tile[N*NP];
    __shared__ float2 sU[JH*N];  // [hj][g]
    __shared__ float2 sE[N*J];   // [r][c]
    int bid = blockIdx.x;
    int tid = threadIdx.x;
    float2 p = scsh[(bid / KBETA) % C];
    const float* src = x + (size_t)bid*N*N;
    for (int i = tid; i < N*N; i += 256){
        int a = i / N, g = i % N;
        tile[a*NP + g] = fmaxf(fmaf(src[i], p.x, p.y), 0.f);
    }
    for (int i = tid; i < N*J; i += 256) sE[i] = EF[i];
    __syncthreads();
    constexpr int HT = (JH+1)/2, GT = N/2;
    for (int t = tid; t < HT*GT; t += 256){
        int tg = t % GT, th = t / GT;
        int h0 = 2*th, g0 = 2*tg;
        int h1 = (h0+1 < JH) ? h0+1 : h0;
        int j0 = c0 + h0, j1 = c0 + h1;
        float2 a00 = make_float2(0.f,0.f), a01 = make_float2(0.f,0.f);
        float2 a10 = make_float2(0.f,0.f), a11 = make_float2(0.f,0.f);
        for (int a = 0; a < N; ++a){
            float v0 = tile[a*NP+g0], v1 = tile[a*NP+g0+1];
            float2 e0 = sE[a*J+j0], e1 = sE[a*J+j1];
            a00.x += v0*e0.x; a00.y += v0*e0.y;
            a01.x += v1*e0.x; a01.y += v1*e0.y;
            a10.x += v0*e1.x; a10.y += v0*e1.y;
            a11.x += v1*e1.x; a11.y += v1*e1.y;
        }
        sU[h0*N+g0] = a00; sU[h0*N+g0+1] = a01;
        if (h0+1 < JH){ sU[(h0+1)*N+g0] = a10; sU[(h0+1)*N+g0+1] = a11; }
    }
    __syncthreads();
    constexpr int NT = (J+1)/2;
    for (int t = tid; t < HT*NT; t += 256){
        int tn = t % NT, th = t / NT;
        int h0 = 2*th, n0 = 2*tn;
        int h1 = (h0+1 < JH) ? h0+1 : h0;
        int n1 = (n0+1 < J) ? n0+1 : n0;
        float2 a00 = make_float2(0.f,0.f), a01 = make_float2(0.f,0.f);
        float2 a10 = make_float2(0.f,0.f), a11 = make_float2(0.f,0.f);
        for (int g = 0; g < N; ++g){
            float2 u0 = sU[h0*N+g], u1 = sU[h1*N+g];
            float2 e0 = sE[g*J+n0], e1 = sE[g*J+n1];
            cadd_mul(a00, u0, e0); cadd_mul(a01, u0, e1);
            cadd_mul(a10, u1, e0); cadd_mul(a11, u1, e1);
        }
        float2* d0 = xh + (size_t)bid*J*J + (size_t)(c0+h0)*J;
        d0[n0] = a00;
        if (n0+1 < J) d0[n0+1] = a01;
        if (h0+1 < JH){
            float2* d1 = xh + (size_t)bid*J*J + (size_t)(c0+h0+1)*J;
            d1[n0] = a10;
            if (n0+1 < J) d1[n0+1] = a11;
        }
    }
}

// Fx rows j>=c0 only (full layout, lower rows never read)
__global__ void k_fx(const float* __restrict__ ana, const float2* __restrict__ xh,
                     float2* __restrict__ Fx, int L, int J, int JH, int K, int BF)
{
    int i = blockIdx.x*blockDim.x + threadIdx.x;
    int JJ = J*J;
    int total = L*JH*J;
    if (i >= total) return;
    int bf = blockIdx.y;
    int n = i % J;
    int hj = (i / J) % JH;
    int l = i / (J*JH);
    int c0 = (J-1)/2;
    int jn = (c0+hj)*J + n;
    const float*  ar = ana + (size_t)l*K*JJ + jn;
    const float2* xr = xh + (size_t)bf*K*JJ + jn;
    float2 acc = make_float2(0.f, 0.f);
    for (int k = 0; k < K; ++k){
        float a = ar[(size_t)k*JJ];
        float2 v = xr[(size_t)k*JJ];
        acc.x += a*v.x; acc.y += a*v.y;
    }
    Fx[((size_t)l*JJ + jn)*BF + bf] = acc;
}

// H rows j>=c0 only (full layout)
__global__ void k_h(const float* __restrict__ half, const float2* __restrict__ Fx,
                    float2* __restrict__ H, int L, int J, int JH, int BF)
{
    int idx = blockIdx.x*blockDim.x + threadIdx.x;
    int total = L*JH*J*BF;
    if (idx >= total) return;
    int bf = idx % BF;
    int n = (idx/BF) % J;
    int hj = (idx/(BF*J)) % JH;
    int l = idx/(BF*J*JH);
    int c0 = (J-1)/2;
    int j = c0 + hj;
    const float* hr = half + (l*J+n)*J;
    const float2* fr = Fx + (size_t)(l*J+j)*J*BF + bf;
    float2 acc = make_float2(0.f, 0.f);
    for (int k = 0; k < J; ++k){
        float h = hr[k];
        float2 v = fr[(size_t)k*BF];
        acc.x += h*v.x; acc.y += h*v.y;
    }
    H[((size_t)(l*J+j)*J + n)*BF + bf] = acc;
}

// LDS-staged GEMM per (n, b): dense packed Z output [bo][(l*JH+hj)*J+n]
__global__ __launch_bounds__(256) void k_zg(const float2* __restrict__ H,
    const float2* __restrict__ wh, float2* __restrict__ Z,
    int L, int J, int JH, int B, int F, int O, float scale)
{
    extern __shared__ float2 smem[];
    float2* swh = smem;           // [F*O]  layout [f*O+o]
    float2* sH  = smem + F*O;     // [F*LH] layout [f*LH+lh]
    int n = blockIdx.x;
    int b = blockIdx.y;
    int tid = threadIdx.x;
    int c0 = (J-1)/2;
    int LH = L*JH;
    int FO = F*O;
    const float2* whn = wh + (size_t)n*FO;
    for (int i = tid; i < FO; i += 256) swh[i] = whn[i];
    for (int i = tid; i < LH*F; i += 256){
        int f = i % F, lh = i / F;
        int l = lh / JH, hj = lh % JH;
        int lj = l*J + c0 + hj;
        sH[f*LH + lh] = H[((size_t)(lj*J + n)*B + b)*F + f];
    }
    __syncthreads();
    int total = O*LH;
    for (int i = tid; i < total; i += 256){
        int lh = i % LH, o = i / LH;
        float2 acc = make_float2(0.f, 0.f);
        for (int f = 0; f < F; ++f)
            cadd_mulc(acc, sH[f*LH + lh], swh[f*O + o]);
        Z[(size_t)(b*O + o)*LH*J + (size_t)lh*J + n] = make_float2(acc.x*scale, acc.y*scale);
    }
}

// ---------------- pool (fused BN+ReLU) + head ----------------
__global__ void k_pool(const float* __restrict__ x, float* __restrict__ pooled, int S,
                       const float2* __restrict__ scsh, int C)
{
    int bid = blockIdx.x;
    float2 p = scsh[bid % C];
    const float* base = x + (long long)bid*S;
    float m = 0.f;   // relu output >= 0
    for (int i = threadIdx.x; i < S; i += blockDim.x)
        m = fmaxf(m, fmaf(base[i], p.x, p.y));
    __shared__ float r[256];
    r[threadIdx.x] = m;
    __syncthreads();
    for (int off = 128; off > 0; off >>= 1){
        if (threadIdx.x < off) r[threadIdx.x] = fmaxf(r[threadIdx.x], r[threadIdx.x+off]);
        __syncthreads();
    }
    if (threadIdx.x == 0) pooled[bid] = fmaxf(r[0], 0.f);
}

__global__ __launch_bounds__(256) void k_final(const float* __restrict__ pooled,
    const float* __restrict__ w, const float* __restrict__ bias, float* __restrict__ out)
{
    __shared__ float pn[1600];
    __shared__ float z[880];
    int tid = threadIdx.x;
    for (int f = tid; f < 100; f += 256){
        float s1 = 0.f, s2 = 0.f;
        for (int b = 0; b < 16; ++b){ float v = pooled[b*100+f]; s1 += v; s2 += v*v; }
        float mu = s1/16.f;
        float var = s2/16.f - mu*mu;
        float inv = rsqrtf(var + 1e-5f);
        for (int b = 0; b < 16; ++b) pn[b*100+f] = (pooled[b*100+f]-mu)*inv;
    }
    __syncthreads();
    for (int i = tid; i < 880; i += 256){
        int c = i % 55, b = i/55;
        float acc = bias[c];
        for (int f = 0; f < 100; ++f) acc += pn[b*100+f]*w[f*55+c];
        z[i] = acc;
    }
    __syncthreads();
    for (int b = tid; b < 16; b += 256){
        float m = -1e30f;
        for (int c = 0; c < 55; ++c) m = fmaxf(m, z[b*55+c]);
        float s = 0.f;
        for (int c = 0; c < 55; ++c) s += expf(z[b*55+c]-m);
        float lse = m + logf(s);
        for (int c = 0; c < 55; ++c) out[b*55+c] = z[b*55+c]-lse;
    }
}

// ---------------- launch ----------------
static inline int cdiv(long long a, long long b){ return (int)((a + b - 1)/b); }

extern "C" void kernel_launch(void* const* d_in, const int* in_sizes, int n_in,
                              void* d_out, int out_size, void* d_ws, size_t ws_size,
                              hipStream_t stream)
{
    (void)in_sizes; (void)n_in; (void)out_size; (void)ws_size;
    const float* x   = (const float*)d_in[0];
    const float* w1  = (const float*)d_in[1];
    const float* b1  = (const float*)d_in[2];
    const float* g1  = (const float*)d_in[3];
    const float* bt1 = (const float*)d_in[4];
    const float* w2  = (const float*)d_in[5];
    const float* b2  = (const float*)d_in[6];
    const float* g2  = (const float*)d_in[7];
    const float* bt2 = (const float*)d_in[8];
    const float* w3  = (const float*)d_in[9];
    const float* b3  = (const float*)d_in[10];
    const float* g3  = (const float*)d_in[11];
    const float* bt3 = (const float*)d_in[12];
    const float* wo  = (const float*)d_in[13];
    const float* bo  = (const float*)d_in[14];
    float* out = (float*)d_out;
    float* ws  = (float*)d_ws;

    // ---- workspace layout (float offsets) ----
    const size_t O_WQ    = 0;
    const size_t O_S2ANA = 376;
    const size_t O_HALF1 = 100216;
    const size_t O_SYN1  = 100996;
    const size_t O_ANA2  = 1317796;
    const size_t O_HALF2 = 1462196;
    const size_t O_SYN2  = 1465806;
    const size_t O_ANA3  = 1538006;
    const size_t O_HALF3 = 1561666;
    const size_t O_SYN3  = 1562849;
    const size_t O_STATS = 1579412;
    const size_t O_PART  = 1580132;
    const size_t O_EF2   = O_PART + 8192;
    const size_t O_EF3   = O_PART + 9712;
    const size_t O_POOL  = 1596516;
    const size_t O_XH1   = 1598116;
    const size_t O_FX1   = 2556580;
    const size_t O_WH1   = 2706340;
    const size_t O_WH2   = 2715700;
    const size_t O_WH3   = 2761300;
    const size_t O_W1    = 2917300;
    const size_t O_W2    = 2920420;
    const size_t O_W3    = 2921180;
    const size_t O_E1    = 2921544;
    const size_t O_A1    = 2931528;
    const size_t O_A2    = 23411528;

    double* WQd   = (double*)(ws + O_WQ);
    float*  S2ANA = ws + O_S2ANA;
    float*  HALF1 = ws + O_HALF1;
    float*  SYN1  = ws + O_SYN1;
    float*  ANA2  = ws + O_ANA2;
    float*  HALF2 = ws + O_HALF2;
    float*  SYN2  = ws + O_SYN2;
    float*  ANA3  = ws + O_ANA3;
    float*  HALF3 = ws + O_HALF3;
    float*  SYN3  = ws + O_SYN3;
    float2* SCSH  = (float2*)(ws + O_STATS);
    double* PART  = (double*)(ws + O_PART);
    float2* EF2   = (float2*)(ws + O_EF2);
    float2* EF3   = (float2*)(ws + O_EF3);
    float*  POOLED= ws + O_POOL;
    float2* XH1   = (float2*)(ws + O_XH1);
    float2* FX1   = (float2*)(ws + O_FX1);
    float2* WH1   = (float2*)(ws + O_WH1);
    float2* WH2   = (float2*)(ws + O_WH2);
    float2* WH3   = (float2*)(ws + O_WH3);
    float2* W1    = (float2*)(ws + O_W1);
    float2* W2    = (float2*)(ws + O_W2);
    float2* W3    = (float2*)(ws + O_W3);
    float2* E1    = (float2*)(ws + O_E1);
    // arena1 phases
    float*  X1    = ws + O_A1;
    float2* FX2   = (float2*)(ws + O_A1);
    float2* H2    = (float2*)(ws + O_A1 + 2310400);
    float2* Z2    = (float2*)(ws + O_A1 + 4620800);
    float2* XH3   = (float2*)(ws + O_A1);
    float2* FX3   = (float2*)(ws + O_A1 + 6489600);
    float2* H3    = (float2*)(ws + O_A1 + 8760960);
    float2* Z3    = (float2*)(ws + O_A1 + 11032320);
    // arena2 phases
    float2* Z1C   = (float2*)(ws + O_A2);   // packed: 320*5530 c
    float2* XH2   = (float2*)(ws + O_A2);
    float*  X2    = ws + O_A2;
    float*  X3    = ws + O_A2;

    const double F128 = 2.0*PI/128.0;
    const double F40sq = (2.0*PI/40.0)*(2.0*PI/40.0);
    const double F20sq = (2.0*PI/20.0)*(2.0*PI/20.0);

    // ---- constants ----
    k_wq<<<1, 256, 0, stream>>>(WQd);
    k_wig_col <<<cdiv(20*128*20,256),256,0,stream>>>(S2ANA, WQd,     20, 39, 128, 256.0, 0.0,   F128, 1);
    k_wig_col <<<cdiv(20*39,256),    256,0,stream>>>(HALF1, nullptr, 20, 39, 1,   0.0,   PI/2,  1.0,  0);
    k_wig_full<<<cdiv(624000,256),   256,0,stream>>>(SYN1,  nullptr, 20, 39, 40,  80.0,  0.0,   1.0,   1, 1, 1);
    k_wig_full<<<cdiv(76000,256),    256,0,stream>>>(ANA2,  WQd+128, 10, 19, 40,  80.0,  0.0,   F40sq, 0, 0, 1);
    k_wig_full<<<cdiv(3610,256),     256,0,stream>>>(HALF2, nullptr, 10, 19, 1,   0.0,   PI/2,  1.0,   0, 0, 0);
    k_wig_full<<<cdiv(38000,256),    256,0,stream>>>(SYN2,  nullptr, 10, 19, 20,  40.0,  0.0,   1.0,   1, 1, 1);
    k_wig_full<<<cdiv(12740,256),    256,0,stream>>>(ANA3,  WQd+168, 7,  13, 20,  40.0,  0.0,   F20sq, 0, 0, 1);
    k_wig_full<<<cdiv(1183,256),     256,0,stream>>>(HALF3, nullptr, 7,  13, 1,   0.0,   PI/2,  1.0,   0, 0, 0);
    k_wig_full<<<cdiv(8918,256),     256,0,stream>>>(SYN3,  nullptr, 7,  13, 14,  28.0,  0.0,   1.0,   1, 1, 1);
    k_expmat  <<<cdiv(1560,256),256,0,stream>>>(W1, 39, 40, 19, 0, 40, -1.0);
    k_expmat  <<<cdiv(380,256), 256,0,stream>>>(W2, 19, 20,  9, 0, 20, -1.0);
    k_expmat  <<<cdiv(182,256), 256,0,stream>>>(W3, 13, 14,  6, 0, 14, -1.0);
    k_expmat  <<<cdiv(4992,256),256,0,stream>>>(E1, 128, 39, 0, 19, 128, -1.0);
    k_expmat  <<<cdiv(760,256), 256,0,stream>>>(EF2, 40, 19, 0, 9, 40, +1.0);
    k_expmat  <<<cdiv(260,256), 256,0,stream>>>(EF3, 20, 13, 0, 6, 20, +1.0);

    // ---- layer 1 (single pass: packed Z1c for all 16 batches) ----
    k_dft1<<<768,256,0,stream>>>(x, E1, XH1);
    k_fx1 <<<dim3(2,96),256,0,stream>>>(S2ANA, XH1, FX1);
    k_wh  <<<cdiv(4680,256),  256,0,stream>>>(WH1, w1, 39, 128, 6, 20, -1.0);
    k_wh  <<<cdiv(22800,256), 256,0,stream>>>(WH2, w2, 19, 40, 20, 60, +1.0);
    k_wh  <<<cdiv(78000,256), 256,0,stream>>>(WH3, w3, 13, 20, 60, 100, +1.0);
    k_z1  <<<dim3(cdiv(5530,256),320),256,0,stream>>>(FX1, WH1, HALF1, Z1C);
    k_idft_t<20,39,40,2,40,20,256,1><<<320*20,256,0,stream>>>(Z1C, SYN1, W1, b1, X1);
    k_bn_stats<<<dim3(32,20),256,0,stream>>>((const float4*)X1, PART, 16, 20, 16000, 32);
    k_bn_fin  <<<1,256,0,stream>>>(PART, g1, bt1, SCSH, 20, 32, 16.0*64000.0);

    // ---- layer 2 (BN1 fused into dft2 load) ----
    k_dft2_t<40,19><<<12800,256,0,stream>>>(X1, XH2, EF2, SCSH, 40, 20);
    k_fx  <<<dim3(cdiv(1900,256),320),256,0,stream>>>(ANA2, XH2, FX2, 10, 19, 10, 40, 320);
    k_h   <<<cdiv(608000,256),256,0,stream>>>(HALF2, FX2, H2, 10, 19, 10, 320);
    k_zg  <<<dim3(19,16),256,(1200+2000)*sizeof(float2),stream>>>(H2, WH2, Z2, 10, 19, 10, 16, 20, 60, 1.f/sqrtf(800.f));
    k_idft_t<10,19,20,5,20,60,256,0><<<960*4,256,0,stream>>>(Z2, SYN2, W2, b2, X2);
    k_bn_stats<<<dim3(8,60),256,0,stream>>>((const float4*)X2, PART, 16, 60, 2000, 8);
    k_bn_fin  <<<1,256,0,stream>>>(PART, g2, bt2, SCSH+20, 60, 8, 16.0*8000.0);

    // ---- layer 3 (BN2 fused into dft2 load) ----
    k_dft2_t<20,13><<<19200,256,0,stream>>>(X2, XH3, EF3, SCSH+20, 20, 60);
    k_fx  <<<dim3(cdiv(637,256),960),256,0,stream>>>(ANA3, XH3, FX3, 7, 13, 7, 20, 960);
    k_h   <<<cdiv(611520,256),256,0,stream>>>(HALF3, FX3, H3, 7, 13, 7, 960);
    k_zg  <<<dim3(13,16),256,(6000+2940)*sizeof(float2),stream>>>(H3, WH3, Z3, 7, 13, 7, 16, 60, 100, 1.f/sqrtf(1200.f));
    k_idft_t<7,13,14,7,14,100,256,0><<<1600*2,256,0,stream>>>(Z3, SYN3, W3, b3, X3);
    k_bn_stats<<<dim3(8,100),256,0,stream>>>((const float4*)X3, PART, 16, 100, 686, 8);
    k_bn_fin  <<<1,256,0,stream>>>(PART, g3, bt3, SCSH+80, 100, 8, 16.0*2744.0);

    // ---- head (BN3 fused into pool) ----
    k_pool <<<1600,256,0,stream>>>(X3, POOLED, 2744, SCSH+80, 100);
    k_final<<<1,256,0,stream>>>(POOLED, wo, bo, out);
}

// Round 19
// 870.689 us; speedup vs baseline: 1.1651x; 1.1651x over previous
//
#include <hip/hip_runtime.h>
#include <math.h>

#define PI 3.14159265358979323846

// ---------------- helpers ----------------
__device__ inline int iabs(int x){ return x < 0 ? -x : x; }

__device__ __host__ constexpr int packed_off(int l){
    // sum_{m<l} (m+1)(2m+1)
    return ((l-1)*l*(2*l-1))/3 + (3*l*(l-1))/2 + l;
}

__device__ inline void cadd_mul(float2& acc, float2 a, float2 b){ // acc += a*b
    acc.x += a.x*b.x - a.y*b.y;
    acc.y += a.x*b.y + a.y*b.x;
}
__device__ inline void cadd_mulc(float2& acc, float2 a, float2 b){ // acc += a*conj(b)
    acc.x += a.x*b.x + a.y*b.y;
    acc.y += a.y*b.x - a.x*b.y;
}

__device__ inline double dpowi(double x, int n){
    double r = 1.0;
    for (int i = 0; i < n; ++i) r *= x;
    return r;
}

// d^l_{a,b}(beta) = <l a| exp(-i beta Jy) |l b>
__device__ double wigner_d(int l, int a, int b, double beta, const double* sf)
{
    double cb = cos(0.5*beta), sb = sin(0.5*beta);
    int smin = max(0, b - a);
    int smax = min(l + b, l - a);
    if (smin > smax) return 0.0;
    double pref = sqrt(sf[l+a]*sf[l-a]*sf[l+b]*sf[l-b]);
    double t = dpowi(cb, 2*l + b - a - 2*smin) * dpowi(sb, a - b + 2*smin);
    if ((a - b + smin) & 1) t = -t;
    double r = -(sb*sb)/(cb*cb);
    double sum = 0.0;
    for (int s = smin; s <= smax; ++s){
        sum += t / (sf[l+b-s]*sf[s]*sf[a-b+s]*sf[l-a-s]);
        t *= r;
    }
    return pref * sum;
}

// ---------------- constants kernels ----------------
__global__ void k_wq(double* wq)
{
    int i = blockIdx.x*blockDim.x + threadIdx.x;
    int b, k, off;
    if (i < 128){ b = 64; k = i;      off = 0;   }
    else if (i < 168){ b = 20; k = i-128; off = 128; }
    else if (i < 188){ b = 10; k = i-168; off = 168; }
    else return;
    double beta = PI*(2*k+1)/(4.0*b);
    double s = 0.0;
    for (int j = 0; j < b; ++j) s += sin((2*j+1)*beta)/(2*j+1);
    wq[off+k] = (2.0/b)*sin(beta)*s;
}

// jhalf=1: generate only rows j >= c0.
// klayout=0: out[((l*NB+k)*J+j)*J+n];  klayout=1: out[((k*L+l)*J+j)*J+n]
__global__ void k_wig_full(float* __restrict__ out, const double* __restrict__ wq,
                           int L, int J, int NB, double denom, double beta_fix,
                           double factor, int mul2l1, int klayout, int jhalf)
{
    __shared__ double sf[40];
    if (threadIdx.x == 0){ sf[0]=1.0; for (int i=1;i<40;i++) sf[i]=sf[i-1]*i; }
    __syncthreads();
    int c0 = (J-1)/2;
    int JROWS = jhalf ? (J+1)/2 : J;
    int idx = blockIdx.x*blockDim.x + threadIdx.x;
    int total = L*NB*JROWS*J;
    if (idx >= total) return;
    int n = idx % J;
    int jj = (idx/J) % JROWS;
    int j = jhalf ? (c0 + jj) : jj;
    int k = (idx/(J*JROWS)) % NB;
    int l = idx/(J*JROWS*NB);
    int mj = j - c0, mn = n - c0;
    float v = 0.f;
    if (iabs(mj) <= l && iabs(mn) <= l){
        double beta = (denom > 0.0) ? PI*(2*k+1)/denom : beta_fix;
        double d = wigner_d(l, mj, mn, beta, sf);
        double mlt = factor * (mul2l1 ? (2.0*l + 1.0) : 1.0);
        if (wq) mlt *= wq[k];
        v = (float)(d*mlt);
    }
    size_t oidx = klayout ? ((size_t)(k*L + l)*J + j)*J + n
                          : ((size_t)(l*NB + k)*J + j)*J + n;
    out[oidx] = v;
}

// column table [l][k][j]; jhalf=1: only j >= c0
__global__ void k_wig_col(float* __restrict__ out, const double* __restrict__ wq,
                          int L, int J, int NB, double denom, double beta_fix, double factor,
                          int jhalf)
{
    __shared__ double sf[40];
    if (threadIdx.x == 0){ sf[0]=1.0; for (int i=1;i<40;i++) sf[i]=sf[i-1]*i; }
    __syncthreads();
    int c0 = (J-1)/2;
    int JROWS = jhalf ? (J+1)/2 : J;
    int idx = blockIdx.x*blockDim.x + threadIdx.x;
    int total = L*NB*JROWS;
    if (idx >= total) return;
    int jj = idx % JROWS;
    int j = jhalf ? (c0 + jj) : jj;
    int k = (idx/JROWS) % NB;
    int l = idx/(JROWS*NB);
    int mj = j - c0;
    float v = 0.f;
    if (iabs(mj) <= l){
        double beta = (denom > 0.0) ? PI*(2*k+1)/denom : beta_fix;
        double d = wigner_d(l, mj, 0, beta, sf);
        double mlt = factor;
        if (wq) mlt *= wq[k];
        v = (float)(d*mlt);
    }
    out[(size_t)(l*NB + k)*J + j] = v;
}

// out[r*C+c] = exp(sgn*2*pi*i*(r-r0)*(c-c0)/N)
__global__ void k_expmat(float2* __restrict__ out, int R, int C, int r0, int c0, int N, double sgn)
{
    int i = blockIdx.x*blockDim.x + threadIdx.x;
    if (i >= R*C) return;
    int c = i % C, r = i / C;
    double ang = sgn*2.0*PI * (double)((r - r0)*(c - c0)) / (double)N;
    out[i] = make_float2((float)cos(ang), (float)sin(ang));
}

// ---------------- layer 1 ----------------
// only j >= 19 (k_fx1 reads only upper rows)
__global__ __launch_bounds__(256) void k_dft1(const float* __restrict__ x,
    const float2* __restrict__ E1, float2* __restrict__ xh)
{
    __shared__ float2 sE[4992];     // [a:128][j:39]
    __shared__ float rows[2048];    // 16 rows x 128
    int r0 = blockIdx.x * 16;       // row = bf*128+k, 12288 rows, 768 blocks
    int tid = threadIdx.x;
    for (int i = tid; i < 4992; i += 256) sE[i] = E1[i];
    for (int i = tid; i < 2048; i += 256) rows[i] = x[(size_t)r0*128 + i];
    __syncthreads();
    for (int i = tid; i < 320; i += 256){   // i = kl*20 + jj, j = jj+19
        int jj = i % 20, kl = i / 20;
        int j = jj + 19;
        const float* row = &rows[kl*128];
        float2 acc = make_float2(0.f, 0.f);
        for (int a = 0; a < 128; ++a){
            float v = row[a];
            float2 e = sE[a*39 + j];
            acc.x += v*e.x; acc.y += v*e.y;
        }
        xh[(size_t)(r0 + kl)*39 + j] = acc;
    }
}

// Fx1 rows j>=c0 only (full layout, lower rows never read)
__global__ void k_fx1(const float* __restrict__ ana, const float2* __restrict__ xh,
                      float2* __restrict__ Fx)
{
    int i = blockIdx.x*blockDim.x + threadIdx.x;
    if (i >= 400) return;           // l*20+hj, l<20, hj<20
    int hj = i % 20, l = i / 20;
    int j = hj + 19;
    int bf = blockIdx.y;  // 96
    const float*  ar = ana + (size_t)l*4992 + j;
    const float2* xr = xh + (size_t)bf*4992 + j;
    float2 acc = make_float2(0.f, 0.f);
    for (int k = 0; k < 128; ++k){
        float a = ar[k*39];
        float2 v = xr[k*39];
        acc.x += a*v.x; acc.y += a*v.y;
    }
    Fx[(size_t)(l*39 + j)*96 + bf] = acc;
}

// wh[(j*F+f)*O+o]
__global__ void k_wh(float2* __restrict__ wh, const float* __restrict__ w,
                     int J, int P, int F, int O, double sgn)
{
    __shared__ float2 tw[128];
    int tid = threadIdx.x;
    if (tid < P){
        double a = sgn*2.0*PI*tid/P;
        tw[tid] = make_float2((float)cos(a), (float)sin(a));
    }
    __syncthreads();
    int idx = blockIdx.x*blockDim.x + tid;
    if (idx >= J*F*O) return;
    int o = idx % O;
    int f = (idx/O) % F;
    int j = idx/(O*F);
    int mj = j - (J-1)/2;
    int step = ((mj % P) + P) % P;
    const float* wr = w + (f*O+o)*P;
    float2 acc = make_float2(0.f, 0.f);
    int t = 0;
    for (int p = 0; p < P; ++p){
        float v = wr[p];
        acc.x += v*tw[t].x; acc.y += v*tw[t].y;
        t += step; if (t >= P) t -= P;
    }
    wh[idx] = acc;
}

// packed triangular Z1c[bo][ off(l) + hj*(2l+1) + (n-19+l) ] — direct packed-domain map
__global__ void k_z1(const float2* __restrict__ Fx, const float2* __restrict__ wh,
                     const float* __restrict__ half1, float2* __restrict__ Z1c)
{
    int i = blockIdx.x*blockDim.x + threadIdx.x;
    if (i >= 5530) return;
    int bo = blockIdx.y;             // 0..319 (16 b x 20 o)
    int l = 0, off = 0;
    #pragma unroll 1
    while (l < 19){
        int next = off + (l+1)*(2*l+1);
        if (i < next) break;
        off = next; ++l;
    }
    int rem = i - off;
    int w = 2*l + 1;
    int hj = rem / w;
    int n = rem % w + 19 - l;
    int j = hj + 19;
    int b = bo/20, o = bo % 20;
    float h = half1[l*39 + n] * (1.f/sqrtf(128.f*6.f));
    const float2* fx = Fx + (size_t)(l*39 + j)*96 + b*6;
    const float2* wv = wh + (size_t)n*120 + o;
    float2 acc = make_float2(0.f, 0.f);
    for (int f = 0; f < 6; ++f) cadd_mulc(acc, fx[f], wv[(size_t)f*20]);
    Z1c[(size_t)bo*5530 + i] = make_float2(acc.x*h, acc.y*h);
}

// ---------------- generic inverse SO3 transform (Hermitian-folded, multi-k) ----------------
// PACKED=1: Z triangular-packed [bo][off(l)+hj*(2l+1)+(n-c0+l)], PTOT=packed_off(L).
// PACKED=0: Z dense [bo][(l*JH+hj)*J+n].
// Phases 2/3: 2x2 register tiles (measured sweet spot: VGPR~48, minimal bank conflicts).
template<int L, int J, int K, int KB, int N, int O, int BS, int PACKED>
__global__ __launch_bounds__(BS) void k_idft_t(const float2* __restrict__ Z,
    const float* __restrict__ syn, const float2* __restrict__ W,
    const float* __restrict__ bias, float* __restrict__ out)
{
    constexpr int JJ = J*J, NN = N*N, c0 = (J-1)/2;
    constexpr int JH = (J+1)/2;
    constexpr int JHJ = JH*J;
    constexpr int LHJ = L*JHJ;
    constexpr int PTOT = packed_off(L);
    constexpr int KG = K/KB;
    constexpr int SLOTS = (JHJ + BS - 1)/BS;
    __shared__ float2 sM[KB*JHJ];
    __shared__ float2 sT[JH*N];
    __shared__ float2 sW[J*N];
    int bid = blockIdx.x;
    int kg = bid % KG;
    int bo = bid / KG;
    int k0 = kg*KB;
    int tid = threadIdx.x;

    for (int i = tid; i < J*N; i += BS) sW[i] = W[i];

    float2 acc[SLOTS][KB];
    #pragma unroll
    for (int s = 0; s < SLOTS; ++s)
        #pragma unroll
        for (int kb = 0; kb < KB; ++kb) acc[s][kb] = make_float2(0.f, 0.f);
    #pragma unroll
    for (int s = 0; s < SLOTS; ++s){
        int i = tid + s*BS;
        if (i < JHJ){
            int n = i % J, hj = i / J;
            int lmin = max(hj, iabs(n-c0));
            const float*  sbase = syn + (size_t)c0*J + i;
            if (PACKED){
                const float2* zb = Z + (size_t)bo*PTOT;
                int addr = packed_off(lmin) + hj*(2*lmin+1) + (n - c0 + lmin);
                for (int l = lmin; l < L; ++l){
                    float2 z = zb[addr];
                    addr += (l+1)*(2*l+1) + 2*hj + 1;
                    #pragma unroll
                    for (int kb = 0; kb < KB; ++kb){
                        float s_ = sbase[(size_t)((k0+kb)*L + l)*JJ];
                        acc[s][kb].x += s_*z.x; acc[s][kb].y += s_*z.y;
                    }
                }
            } else {
                const float2* zrow = Z + (size_t)bo*LHJ + i;
                for (int l = lmin; l < L; ++l){
                    float2 z = zrow[(size_t)l*JHJ];
                    #pragma unroll
                    for (int kb = 0; kb < KB; ++kb){
                        float s_ = sbase[(size_t)((k0+kb)*L + l)*JJ];
                        acc[s][kb].x += s_*z.x; acc[s][kb].y += s_*z.y;
                    }
                }
            }
        }
    }
    #pragma unroll
    for (int s = 0; s < SLOTS; ++s){
        int i = tid + s*BS;
        if (i < JHJ){
            #pragma unroll
            for (int kb = 0; kb < KB; ++kb) sM[kb*JHJ + i] = acc[s][kb];
        }
    }
    __syncthreads();

    constexpr int RT = (JH+1)/2, CT = N/2;
    for (int kb = 0; kb < KB; ++kb){
        const float2* sMk = &sM[kb*JHJ];
        // phase 2: sT[hj*N+g] = sum_n sMk[hj*J+n]*sW[n*N+g]  (2x2 tile)
        for (int t = tid; t < RT*CT; t += BS){
            int tg = t % CT, tj = t / CT;
            int h0 = tj*2, g0 = tg*2;
            int h1 = (h0+1 < JH) ? h0+1 : h0;
            float2 a00 = make_float2(0.f,0.f), a01 = make_float2(0.f,0.f);
            float2 a10 = make_float2(0.f,0.f), a11 = make_float2(0.f,0.f);
            for (int n = 0; n < J; ++n){
                float2 w0 = sW[n*N+g0], w1 = sW[n*N+g0+1];
                float2 m0 = sMk[h0*J+n], m1 = sMk[h1*J+n];
                cadd_mul(a00, m0, w0); cadd_mul(a01, m0, w1);
                cadd_mul(a10, m1, w0); cadd_mul(a11, m1, w1);
            }
            sT[h0*N+g0] = a00; sT[h0*N+g0+1] = a01;
            if (h0+1 < JH){ sT[(h0+1)*N+g0] = a10; sT[(h0+1)*N+g0+1] = a11; }
        }
        __syncthreads();
        // phase 3 (2x2 tile over (a,g))
        float bb = bias[bo % O];
        float* obase = out + ((size_t)bo*K + k0 + kb)*NN;
        for (int t = tid; t < CT*CT; t += BS){
            int tg = t % CT, ta = t / CT;
            int a0 = ta*2, g0 = tg*2;
            float2 t00 = sT[g0], t01 = sT[g0+1];   // hj = 0 row (W row c0 = 1)
            float r00 = t00.x, r01 = t01.x, r10 = t00.x, r11 = t01.x;
            for (int hj = 1; hj < JH; ++hj){
                float2 wa0 = sW[(c0+hj)*N+a0], wa1 = sW[(c0+hj)*N+a0+1];
                float2 t0 = sT[hj*N+g0], t1 = sT[hj*N+g0+1];
                r00 += 2.f*(t0.x*wa0.x - t0.y*wa0.y);
                r01 += 2.f*(t1.x*wa0.x - t1.y*wa0.y);
                r10 += 2.f*(t0.x*wa1.x - t0.y*wa1.y);
                r11 += 2.f*(t1.x*wa1.x - t1.y*wa1.y);
            }
            obase[(a0+0)*N+g0]   = r00 + bb;
            obase[(a0+0)*N+g0+1] = r01 + bb;
            obase[(a0+1)*N+g0]   = r10 + bb;
            obase[(a0+1)*N+g0+1] = r11 + bb;
        }
        __syncthreads();
    }
}

// ---------------- BN stats (float4) ----------------
__global__ __launch_bounds__(256) void k_bn_stats(const float4* __restrict__ x, double* __restrict__ part,
                                                  int B, int C, int S4, int parts)
{
    int c = blockIdx.y, p = blockIdx.x;
    int chunk = (S4 + parts - 1)/parts;
    int s0 = p*chunk, s1e = min(S4, s0 + chunk);
    double a1 = 0.0, a2 = 0.0;
    for (int b = 0; b < B; ++b){
        const float4* base = x + ((size_t)b*C + c)*S4;
        for (int s = s0 + threadIdx.x; s < s1e; s += 256){
            float4 v = base[s];
            a1 += (double)v.x + (double)v.y + (double)v.z + (double)v.w;
            a2 += (double)v.x*v.x + (double)v.y*v.y + (double)v.z*v.z + (double)v.w*v.w;
        }
    }
    __shared__ double r1[256], r2[256];
    r1[threadIdx.x] = a1; r2[threadIdx.x] = a2;
    __syncthreads();
    for (int off = 128; off > 0; off >>= 1){
        if (threadIdx.x < off){ r1[threadIdx.x] += r1[threadIdx.x+off]; r2[threadIdx.x] += r2[threadIdx.x+off]; }
        __syncthreads();
    }
    if (threadIdx.x == 0){ int bid = p*C + c; part[2*bid] = r1[0]; part[2*bid+1] = r2[0]; }
}

__global__ void k_bn_fin(const double* __restrict__ part, const float* __restrict__ g,
                         const float* __restrict__ bt, float2* __restrict__ scsh,
                         int C, int parts, double cnt)
{
    int c = blockIdx.x*blockDim.x + threadIdx.x;
    if (c >= C) return;
    double s1 = 0.0, s2 = 0.0;
    for (int p = 0; p < parts; ++p){ s1 += part[2*(p*C+c)]; s2 += part[2*(p*C+c)+1]; }
    double mu = s1/cnt;
    double var = s2/cnt - mu*mu;
    float sc = (float)(1.0/sqrt(var + 1e-5)) * g[c];
    float sh = bt[c] - (float)mu*sc;
    scsh[c] = make_float2(sc, sh);
}

// ---------------- SO3 layers (2,3) ----------------
// forward 2D DFT with fused BN+ReLU at tile load; j-first ordering.
template<int N, int J>
__global__ __launch_bounds__(256) void k_dft2_t(const float* __restrict__ x, float2* __restrict__ xh,
                                                const float2* __restrict__ EF,
                                                const float2* __restrict__ scsh, int KBETA, int C)
{
    constexpr int JH = (J+1)/2, c0 = (J-1)/2;
    constexpr int NP = N+1;
    __shared__ float tile[N*NP];
    __shared__ float2 sU[JH*N];  // [hj][g]
    __shared__ float2 sE[N*J];   // [r][c]
    int bid = blockIdx.x;
    int tid = threadIdx.x;
    float2 p = scsh[(bid / KBETA) % C];
    const float* src = x + (size_t)bid*N*N;
    for (int i = tid; i < N*N; i += 256){
        int a = i / N, g = i % N;
        tile[a*NP + g] = fmaxf(fmaf(src[i], p.x, p.y), 0.f);
    }
    for (int i = tid; i < N*J; i += 256) sE[i] = EF[i];
    __syncthreads();
    constexpr int HT = (JH+1)/2, GT = N/2;
    for (int t = tid; t < HT*GT; t += 256){
        int tg = t % GT, th = t / GT;
        int h0 = 2*th, g0 = 2*tg;
        int h1 = (h0+1 < JH) ? h0+1 : h0;
        int j0 = c0 + h0, j1 = c0 + h1;
        float2 a00 = make_float2(0.f,0.f), a01 = make_float2(0.f,0.f);
        float2 a10 = make_float2(0.f,0.f), a11 = make_float2(0.f,0.f);
        for (int a = 0; a < N; ++a){
            float v0 = tile[a*NP+g0], v1 = tile[a*NP+g0+1];
            float2 e0 = sE[a*J+j0], e1 = sE[a*J+j1];
            a00.x += v0*e0.x; a00.y += v0*e0.y;
            a01.x += v1*e0.x; a01.y += v1*e0.y;
            a10.x += v0*e1.x; a10.y += v0*e1.y;
            a11.x += v1*e1.x; a11.y += v1*e1.y;
        }
        sU[h0*N+g0] = a00; sU[h0*N+g0+1] = a01;
        if (h0+1 < JH){ sU[(h0+1)*N+g0] = a10; sU[(h0+1)*N+g0+1] = a11; }
    }
    __syncthreads();
    constexpr int NT = (J+1)/2;
    for (int t = tid; t < HT*NT; t += 256){
        int tn = t % NT, th = t / NT;
        int h0 = 2*th, n0 = 2*tn;
        int h1 = (h0+1 < JH) ? h0+1 : h0;
        int n1 = (n0+1 < J) ? n0+1 : n0;
        float2 a00 = make_float2(0.f,0.f), a01 = make_float2(0.f,0.f);
        float2 a10 = make_float2(0.f,0.f), a11 = make_float2(0.f,0.f);
        for (int g = 0; g < N; ++g){
            float2 u0 = sU[h0*N+g], u1 = sU[h1*N+g];
            float2 e0 = sE[g*J+n0], e1 = sE[g*J+n1];
            cadd_mul(a00, u0, e0); cadd_mul(a01, u0, e1);
            cadd_mul(a10, u1, e0); cadd_mul(a11, u1, e1);
        }
        float2* d0 = xh + (size_t)bid*J*J + (size_t)(c0+h0)*J;
        d0[n0] = a00;
        if (n0+1 < J) d0[n0+1] = a01;
        if (h0+1 < JH){
            float2* d1 = xh + (size_t)bid*J*J + (size_t)(c0+h0+1)*J;
            d1[n0] = a10;
            if (n0+1 < J) d1[n0+1] = a11;
        }
    }
}

// Fx rows j>=c0 only (full layout, lower rows never read)
__global__ void k_fx(const float* __restrict__ ana, const float2* __restrict__ xh,
                     float2* __restrict__ Fx, int L, int J, int JH, int K, int BF)
{
    int i = blockIdx.x*blockDim.x + threadIdx.x;
    int JJ = J*J;
    int total = L*JH*J;
    if (i >= total) return;
    int bf = blockIdx.y;
    int n = i % J;
    int hj = (i / J) % JH;
    int l = i / (J*JH);
    int c0 = (J-1)/2;
    int jn = (c0+hj)*J + n;
    const float*  ar = ana + (size_t)l*K*JJ + jn;
    const float2* xr = xh + (size_t)bf*K*JJ + jn;
    float2 acc = make_float2(0.f, 0.f);
    for (int k = 0; k < K; ++k){
        float a = ar[(size_t)k*JJ];
        float2 v = xr[(size_t)k*JJ];
        acc.x += a*v.x; acc.y += a*v.y;
    }
    Fx[((size_t)l*JJ + jn)*BF + bf] = acc;
}

// H rows j>=c0 only (full layout)
__global__ void k_h(const float* __restrict__ half, const float2* __restrict__ Fx,
                    float2* __restrict__ H, int L, int J, int JH, int BF)
{
    int idx = blockIdx.x*blockDim.x + threadIdx.x;
    int total = L*JH*J*BF;
    if (idx >= total) return;
    int bf = idx % BF;
    int n = (idx/BF) % J;
    int hj = (idx/(BF*J)) % JH;
    int l = idx/(BF*J*JH);
    int c0 = (J-1)/2;
    int j = c0 + hj;
    const float* hr = half + (l*J+n)*J;
    const float2* fr = Fx + (size_t)(l*J+j)*J*BF + bf;
    float2 acc = make_float2(0.f, 0.f);
    for (int k = 0; k < J; ++k){
        float h = hr[k];
        float2 v = fr[(size_t)k*BF];
        acc.x += h*v.x; acc.y += h*v.y;
    }
    H[((size_t)(l*J+j)*J + n)*BF + bf] = acc;
}

// LDS-staged GEMM per (n, b): dense packed Z output [bo][(l*JH+hj)*J+n]
__global__ __launch_bounds__(256) void k_zg(const float2* __restrict__ H,
    const float2* __restrict__ wh, float2* __restrict__ Z,
    int L, int J, int JH, int B, int F, int O, float scale)
{
    extern __shared__ float2 smem[];
    float2* swh = smem;           // [F*O]  layout [f*O+o]
    float2* sH  = smem + F*O;     // [F*LH] layout [f*LH+lh]
    int n = blockIdx.x;
    int b = blockIdx.y;
    int tid = threadIdx.x;
    int c0 = (J-1)/2;
    int LH = L*JH;
    int FO = F*O;
    const float2* whn = wh + (size_t)n*FO;
    for (int i = tid; i < FO; i += 256) swh[i] = whn[i];
    for (int i = tid; i < LH*F; i += 256){
        int f = i % F, lh = i / F;
        int l = lh / JH, hj = lh % JH;
        int lj = l*J + c0 + hj;
        sH[f*LH + lh] = H[((size_t)(lj*J + n)*B + b)*F + f];
    }
    __syncthreads();
    int total = O*LH;
    for (int i = tid; i < total; i += 256){
        int lh = i % LH, o = i / LH;
        float2 acc = make_float2(0.f, 0.f);
        for (int f = 0; f < F; ++f)
            cadd_mulc(acc, sH[f*LH + lh], swh[f*O + o]);
        Z[(size_t)(b*O + o)*LH*J + (size_t)lh*J + n] = make_float2(acc.x*scale, acc.y*scale);
    }
}

// ---------------- pool (fused BN+ReLU) + head ----------------
__global__ void k_pool(const float* __restrict__ x, float* __restrict__ pooled, int S,
                       const float2* __restrict__ scsh, int C)
{
    int bid = blockIdx.x;
    float2 p = scsh[bid % C];
    const float* base = x + (long long)bid*S;
    float m = 0.f;   // relu output >= 0
    for (int i = threadIdx.x; i < S; i += blockDim.x)
        m = fmaxf(m, fmaf(base[i], p.x, p.y));
    __shared__ float r[256];
    r[threadIdx.x] = m;
    __syncthreads();
    for (int off = 128; off > 0; off >>= 1){
        if (threadIdx.x < off) r[threadIdx.x] = fmaxf(r[threadIdx.x], r[threadIdx.x+off]);
        __syncthreads();
    }
    if (threadIdx.x == 0) pooled[bid] = fmaxf(r[0], 0.f);
}

__global__ __launch_bounds__(256) void k_final(const float* __restrict__ pooled,
    const float* __restrict__ w, const float* __restrict__ bias, float* __restrict__ out)
{
    __shared__ float pn[1600];
    __shared__ float z[880];
    int tid = threadIdx.x;
    for (int f = tid; f < 100; f += 256){
        float s1 = 0.f, s2 = 0.f;
        for (int b = 0; b < 16; ++b){ float v = pooled[b*100+f]; s1 += v; s2 += v*v; }
        float mu = s1/16.f;
        float var = s2/16.f - mu*mu;
        float inv = rsqrtf(var + 1e-5f);
        for (int b = 0; b < 16; ++b) pn[b*100+f] = (pooled[b*100+f]-mu)*inv;
    }
    __syncthreads();
    for (int i = tid; i < 880; i += 256){
        int c = i % 55, b = i/55;
        float acc = bias[c];
        for (int f = 0; f < 100; ++f) acc += pn[b*100+f]*w[f*55+c];
        z[i] = acc;
    }
    __syncthreads();
    for (int b = tid; b < 16; b += 256){
        float m = -1e30f;
        for (int c = 0; c < 55; ++c) m = fmaxf(m, z[b*55+c]);
        float s = 0.f;
        for (int c = 0; c < 55; ++c) s += expf(z[b*55+c]-m);
        float lse = m + logf(s);
        for (int c = 0; c < 55; ++c) out[b*55+c] = z[b*55+c]-lse;
    }
}

// ---------------- launch ----------------
static inline int cdiv(long long a, long long b){ return (int)((a + b - 1)/b); }

extern "C" void kernel_launch(void* const* d_in, const int* in_sizes, int n_in,
                              void* d_out, int out_size, void* d_ws, size_t ws_size,
                              hipStream_t stream)
{
    (void)in_sizes; (void)n_in; (void)out_size; (void)ws_size;
    const float* x   = (const float*)d_in[0];
    const float* w1  = (const float*)d_in[1];
    const float* b1  = (const float*)d_in[2];
    const float* g1  = (const float*)d_in[3];
    const float* bt1 = (const float*)d_in[4];
    const float* w2  = (const float*)d_in[5];
    const float* b2  = (const float*)d_in[6];
    const float* g2  = (const float*)d_in[7];
    const float* bt2 = (const float*)d_in[8];
    const float* w3  = (const float*)d_in[9];
    const float* b3  = (const float*)d_in[10];
    const float* g3  = (const float*)d_in[11];
    const float* bt3 = (const float*)d_in[12];
    const float* wo  = (const float*)d_in[13];
    const float* bo  = (const float*)d_in[14];
    float* out = (float*)d_out;
    float* ws  = (float*)d_ws;

    // ---- workspace layout (float offsets) ----
    const size_t O_WQ    = 0;
    const size_t O_S2ANA = 376;
    const size_t O_HALF1 = 100216;
    const size_t O_SYN1  = 100996;
    const size_t O_ANA2  = 1317796;
    const size_t O_HALF2 = 1462196;
    const size_t O_SYN2  = 1465806;
    const size_t O_ANA3  = 1538006;
    const size_t O_HALF3 = 1561666;
    const size_t O_SYN3  = 1562849;
    const size_t O_STATS = 1579412;
    const size_t O_PART  = 1580132;
    const size_t O_EF2   = O_PART + 8192;
    const size_t O_EF3   = O_PART + 9712;
    const size_t O_POOL  = 1596516;
    const size_t O_XH1   = 1598116;
    const size_t O_FX1   = 2556580;
    const size_t O_WH1   = 2706340;
    const size_t O_WH2   = 2715700;
    const size_t O_WH3   = 2761300;
    const size_t O_W1    = 2917300;
    const size_t O_W2    = 2920420;
    const size_t O_W3    = 2921180;
    const size_t O_E1    = 2921544;
    const size_t O_A1    = 2931528;
    const size_t O_A2    = 23411528;

    double* WQd   = (double*)(ws + O_WQ);
    float*  S2ANA = ws + O_S2ANA;
    float*  HALF1 = ws + O_HALF1;
    float*  SYN1  = ws + O_SYN1;
    float*  ANA2  = ws + O_ANA2;
    float*  HALF2 = ws + O_HALF2;
    float*  SYN2  = ws + O_SYN2;
    float*  ANA3  = ws + O_ANA3;
    float*  HALF3 = ws + O_HALF3;
    float*  SYN3  = ws + O_SYN3;
    float2* SCSH  = (float2*)(ws + O_STATS);
    double* PART  = (double*)(ws + O_PART);
    float2* EF2   = (float2*)(ws + O_EF2);
    float2* EF3   = (float2*)(ws + O_EF3);
    float*  POOLED= ws + O_POOL;
    float2* XH1   = (float2*)(ws + O_XH1);
    float2* FX1   = (float2*)(ws + O_FX1);
    float2* WH1   = (float2*)(ws + O_WH1);
    float2* WH2   = (float2*)(ws + O_WH2);
    float2* WH3   = (float2*)(ws + O_WH3);
    float2* W1    = (float2*)(ws + O_W1);
    float2* W2    = (float2*)(ws + O_W2);
    float2* W3    = (float2*)(ws + O_W3);
    float2* E1    = (float2*)(ws + O_E1);
    // arena1 phases
    float*  X1    = ws + O_A1;
    float2* FX2   = (float2*)(ws + O_A1);
    float2* H2    = (float2*)(ws + O_A1 + 2310400);
    float2* Z2    = (float2*)(ws + O_A1 + 4620800);
    float2* XH3   = (float2*)(ws + O_A1);
    float2* FX3   = (float2*)(ws + O_A1 + 6489600);
    float2* H3    = (float2*)(ws + O_A1 + 8760960);
    float2* Z3    = (float2*)(ws + O_A1 + 11032320);
    // arena2 phases
    float2* Z1C   = (float2*)(ws + O_A2);   // packed: 320*5530 c
    float2* XH2   = (float2*)(ws + O_A2);
    float*  X2    = ws + O_A2;
    float*  X3    = ws + O_A2;

    const double F128 = 2.0*PI/128.0;
    const double F40sq = (2.0*PI/40.0)*(2.0*PI/40.0);
    const double F20sq = (2.0*PI/20.0)*(2.0*PI/20.0);

    // ---- constants ----
    k_wq<<<1, 256, 0, stream>>>(WQd);
    k_wig_col <<<cdiv(20*128*20,256),256,0,stream>>>(S2ANA, WQd,     20, 39, 128, 256.0, 0.0,   F128, 1);
    k_wig_col <<<cdiv(20*39,256),    256,0,stream>>>(HALF1, nullptr, 20, 39, 1,   0.0,   PI/2,  1.0,  0);
    k_wig_full<<<cdiv(624000,256),   256,0,stream>>>(SYN1,  nullptr, 20, 39, 40,  80.0,  0.0,   1.0,   1, 1, 1);
    k_wig_full<<<cdiv(76000,256),    256,0,stream>>>(ANA2,  WQd+128, 10, 19, 40,  80.0,  0.0,   F40sq, 0, 0, 1);
    k_wig_full<<<cdiv(3610,256),     256,0,stream>>>(HALF2, nullptr, 10, 19, 1,   0.0,   PI/2,  1.0,   0, 0, 0);
    k_wig_full<<<cdiv(38000,256),    256,0,stream>>>(SYN2,  nullptr, 10, 19, 20,  40.0,  0.0,   1.0,   1, 1, 1);
    k_wig_full<<<cdiv(12740,256),    256,0,stream>>>(ANA3,  WQd+168, 7,  13, 20,  40.0,  0.0,   F20sq, 0, 0, 1);
    k_wig_full<<<cdiv(1183,256),     256,0,stream>>>(HALF3, nullptr, 7,  13, 1,   0.0,   PI/2,  1.0,   0, 0, 0);
    k_wig_full<<<cdiv(8918,256),     256,0,stream>>>(SYN3,  nullptr, 7,  13, 14,  28.0,  0.0,   1.0,   1, 1, 1);
    k_expmat  <<<cdiv(1560,256),256,0,stream>>>(W1, 39, 40, 19, 0, 40, -1.0);
    k_expmat  <<<cdiv(380,256), 256,0,stream>>>(W2, 19, 20,  9, 0, 20, -1.0);
    k_expmat  <<<cdiv(182,256), 256,0,stream>>>(W3, 13, 14,  6, 0, 14, -1.0);
    k_expmat  <<<cdiv(4992,256),256,0,stream>>>(E1, 128, 39, 0, 19, 128, -1.0);
    k_expmat  <<<cdiv(760,256), 256,0,stream>>>(EF2, 40, 19, 0, 9, 40, +1.0);
    k_expmat  <<<cdiv(260,256), 256,0,stream>>>(EF3, 20, 13, 0, 6, 20, +1.0);

    // ---- layer 1 (single pass: packed Z1c for all 16 batches) ----
    k_dft1<<<768,256,0,stream>>>(x, E1, XH1);
    k_fx1 <<<dim3(2,96),256,0,stream>>>(S2ANA, XH1, FX1);
    k_wh  <<<cdiv(4680,256),  256,0,stream>>>(WH1, w1, 39, 128, 6, 20, -1.0);
    k_wh  <<<cdiv(22800,256), 256,0,stream>>>(WH2, w2, 19, 40, 20, 60, +1.0);
    k_wh  <<<cdiv(78000,256), 256,0,stream>>>(WH3, w3, 13, 20, 60, 100, +1.0);
    k_z1  <<<dim3(cdiv(5530,256),320),256,0,stream>>>(FX1, WH1, HALF1, Z1C);
    k_idft_t<20,39,40,2,40,20,256,1><<<320*20,256,0,stream>>>(Z1C, SYN1, W1, b1, X1);
    k_bn_stats<<<dim3(32,20),256,0,stream>>>((const float4*)X1, PART, 16, 20, 16000, 32);
    k_bn_fin  <<<1,256,0,stream>>>(PART, g1, bt1, SCSH, 20, 32, 16.0*64000.0);

    // ---- layer 2 (BN1 fused into dft2 load) ----
    k_dft2_t<40,19><<<12800,256,0,stream>>>(X1, XH2, EF2, SCSH, 40, 20);
    k_fx  <<<dim3(cdiv(1900,256),320),256,0,stream>>>(ANA2, XH2, FX2, 10, 19, 10, 40, 320);
    k_h   <<<cdiv(608000,256),256,0,stream>>>(HALF2, FX2, H2, 10, 19, 10, 320);
    k_zg  <<<dim3(19,16),256,(1200+2000)*sizeof(float2),stream>>>(H2, WH2, Z2, 10, 19, 10, 16, 20, 60, 1.f/sqrtf(800.f));
    k_idft_t<10,19,20,5,20,60,256,0><<<960*4,256,0,stream>>>(Z2, SYN2, W2, b2, X2);
    k_bn_stats<<<dim3(8,60),256,0,stream>>>((const float4*)X2, PART, 16, 60, 2000, 8);
    k_bn_fin  <<<1,256,0,stream>>>(PART, g2, bt2, SCSH+20, 60, 8, 16.0*8000.0);

    // ---- layer 3 (BN2 fused into dft2 load) ----
    k_dft2_t<20,13><<<19200,256,0,stream>>>(X2, XH3, EF3, SCSH+20, 20, 60);
    k_fx  <<<dim3(cdiv(637,256),960),256,0,stream>>>(ANA3, XH3, FX3, 7, 13, 7, 20, 960);
    k_h   <<<cdiv(611520,256),256,0,stream>>>(HALF3, FX3, H3, 7, 13, 7, 960);
    k_zg  <<<dim3(13,16),256,(6000+2940)*sizeof(float2),stream>>>(H3, WH3, Z3, 7, 13, 7, 16, 60, 100, 1.f/sqrtf(1200.f));
    k_idft_t<7,13,14,7,14,100,256,0><<<1600*2,256,0,stream>>>(Z3, SYN3, W3, b3, X3);
    k_bn_stats<<<dim3(8,100),256,0,stream>>>((const float4*)X3, PART, 16, 100, 686, 8);
    k_bn_fin  <<<1,256,0,stream>>>(PART, g3, bt3, SCSH+80, 100, 8, 16.0*2744.0);

    // ---- head (BN3 fused into pool) ----
    k_pool <<<1600,256,0,stream>>>(X3, POOLED, 2744, SCSH+80, 100);
    k_final<<<1,256,0,stream>>>(POOLED, wo, bo, out);
}